// Round 4
// baseline (16489.507 us; speedup 1.0000x reference)
//
#include <hip/hip_runtime.h>
#include <hip/hip_fp16.h>

// Persistent 2D-LSTM. B=64, NC=512, T=1024, P=8, F=192, K_total=1216.
// 128 WGs x 512 thr; each WG owns 4 channels x 4 gates = 16 gate-columns.
// Weights fp16 in LDS (loaded once; immune to cache-inv and regalloc).
// Cross-WG sync: done[] counters (agent atomics); h via 64-slot fp16 ring in
// MFMA A-fragment layout. Ring half index: slot*32768 + (ch>>3)*512 + b*8 + (ch&7).

typedef __attribute__((ext_vector_type(8))) _Float16 half8;
typedef __attribute__((ext_vector_type(4))) float f32x4;

#define T_    1024
#define NWG   128

// ws layout: done[1024*8] u32 at 0 (32 KB), ring at 32768 (64*512*64*2 = 4 MB)
#define OFF_RING 32768

__global__ __launch_bounds__(512, 1) void lstm_persist(
    const float* __restrict__ x, const float* __restrict__ Wih,
    const float* __restrict__ Whh, const float* __restrict__ bih,
    const float* __restrict__ bhh, float* __restrict__ out,
    _Float16* ring, unsigned* done)
{
    __shared__ _Float16 Wsm[38 * 64 * 8];   // 38,912 B: [chunk c][lane l] half8
    __shared__ float Psm[4][64][17];        // 17,408 B: K-group partials
    __shared__ float cst[256];              //  1,024 B: c-state [b][ch_local]

    const int tid = threadIdx.x;
    const int l   = tid & 63;
    const int wv  = tid >> 6;     // wave 0..7
    const int ks  = wv & 3;       // K-group: chunks c with c%4==ks
    const int mh  = wv >> 2;      // batch half 0..1
    const int w   = blockIdx.x;   // 0..127: owns channels w*4..w*4+3 (all 4 gates)
    const int l15 = l & 15, l4 = l >> 4;

    // ---- weight prologue: fp32 -> fp16 fragments into LDS (once) ----
    // col (0..15) -> gate row rj = (col&3)*512 + w*4 + (col>>2)
    for (int c = wv; c < 38; c += 8) {
        const int rj = (l15 & 3) * 512 + w * 4 + (l15 >> 2);
        const float* src = (c < 22)
            ? (Wih + (size_t)rj * 704 + c * 32 + l4 * 8)
            : (Whh + (size_t)rj * 512 + (c - 22) * 32 + l4 * 8);
        float4 v0 = ((const float4*)src)[0];
        float4 v1 = ((const float4*)src)[1];
        half8 hb;
        hb[0] = (_Float16)v0.x; hb[1] = (_Float16)v0.y;
        hb[2] = (_Float16)v0.z; hb[3] = (_Float16)v0.w;
        hb[4] = (_Float16)v1.x; hb[5] = (_Float16)v1.y;
        hb[6] = (_Float16)v1.z; hb[7] = (_Float16)v1.w;
        *(half8*)(Wsm + (size_t)(c * 64 + l) * 8) = hb;
    }
    if (tid < 256) cst[tid] = 0.f;

    // ---- pointwise role: thread (pb, pc); only tid<256 active there ----
    const int pb = tid >> 2, pc = tid & 3;        // pb 0..127 but used only <64
    const int gc = w * 4 + (tid & 3);             // global channel for pointwise
    const float bI = bih[gc]        + bhh[gc];
    const float bF = bih[512 + gc]  + bhh[512 + gc];
    const float bG = bih[1024 + gc] + bhh[1024 + gc];
    const float bO = bih[1536 + gc] + bhh[1536 + gc];
    __syncthreads();

    const half8* rp = (const half8*)ring;

    for (int t = 0; t < T_; ++t) {
        f32x4 acc[2];
        acc[0] = (f32x4){0.f, 0.f, 0.f, 0.f};
        acc[1] = (f32x4){0.f, 0.f, 0.f, 0.f};

        const int y = t >> 5, xc = t & 31;

        // ---- pass 1a: x chunks (c = 0..5), fp32->fp16 on the fly ----
#pragma unroll
        for (int c = 0; c < 6; ++c) {
            if ((c & 3) != ks) continue;
            const half8 bf = *(const half8*)(Wsm + (size_t)(c * 64 + l) * 8);
#pragma unroll
            for (int ii = 0; ii < 2; ++ii) {
                const int b  = (mh * 2 + ii) * 16 + l15;
                const int k0 = c * 32 + l4 * 8;
                const float* xs = x + ((size_t)(b * 3 + (k0 >> 6)) * 256
                                       + y * 8 + ((k0 >> 3) & 7)) * 256 + xc * 8;
                float4 v0 = ((const float4*)xs)[0];
                float4 v1 = ((const float4*)xs)[1];
                half8 a;
                a[0] = (_Float16)v0.x; a[1] = (_Float16)v0.y;
                a[2] = (_Float16)v0.z; a[3] = (_Float16)v0.w;
                a[4] = (_Float16)v1.x; a[5] = (_Float16)v1.y;
                a[6] = (_Float16)v1.z; a[7] = (_Float16)v1.w;
                acc[ii] = __builtin_amdgcn_mfma_f32_16x16x32_f16(a, bf, acc[ii], 0, 0, 0);
            }
        }
        // ---- pass 1b: h(t-32) chunks (c = 6..21), before the wait ----
        if (t >= 32) {
            const int sO = (t - 32) & 63;
#pragma unroll
            for (int c = 6; c < 22; ++c) {
                if ((c & 3) != ks) continue;
                const half8 bf = *(const half8*)(Wsm + (size_t)(c * 64 + l) * 8);
#pragma unroll
                for (int ii = 0; ii < 2; ++ii) {
                    const int b = (mh * 2 + ii) * 16 + l15;
                    half8 a = rp[(size_t)sO * 4096 + (size_t)((c - 6) * 4 + l4) * 64 + b];
                    acc[ii] = __builtin_amdgcn_mfma_f32_16x16x32_f16(a, bf, acc[ii], 0, 0, 0);
                }
            }
        }

        // ---- wait for all WGs to have published h(t-1) ----
        if (t > 0) {
            if (tid == 0) {
                unsigned* dp = done + (size_t)(t - 1) * 8;
                unsigned s;
                do {
                    s = 0;
#pragma unroll
                    for (int i = 0; i < 8; ++i)
                        s += __hip_atomic_load(dp + i, __ATOMIC_RELAXED, __HIP_MEMORY_SCOPE_AGENT);
                    if (s < NWG) __builtin_amdgcn_s_sleep(1);
                } while (s < NWG);
            }
        }
        __syncthreads();
        // ---- pass 2: h(t-1) chunks (c = 22..37) ----
        if (t > 0) {
            __builtin_amdgcn_fence(__ATOMIC_ACQUIRE, "agent");
            const int sP = (t - 1) & 63;
#pragma unroll
            for (int c = 22; c < 38; ++c) {
                if ((c & 3) != ks) continue;
                const half8 bf = *(const half8*)(Wsm + (size_t)(c * 64 + l) * 8);
#pragma unroll
                for (int ii = 0; ii < 2; ++ii) {
                    const int b = (mh * 2 + ii) * 16 + l15;
                    half8 a = rp[(size_t)sP * 4096 + (size_t)((c - 22) * 4 + l4) * 64 + b];
                    acc[ii] = __builtin_amdgcn_mfma_f32_16x16x32_f16(a, bf, acc[ii], 0, 0, 0);
                }
            }
        }

        // ---- K-group partials -> LDS ----
#pragma unroll
        for (int ii = 0; ii < 2; ++ii)
#pragma unroll
            for (int r = 0; r < 4; ++r)
                Psm[ks][(mh * 2 + ii) * 16 + l4 * 4 + r][l15] = acc[ii][r];
        __syncthreads();

        // ---- fused LSTM pointwise (tid < 256: thread = (batch pb, ch pc)) ----
        if (tid < 256) {
            float gi = bI, gf = bF, gg = bG, go = bO;
#pragma unroll
            for (int k4 = 0; k4 < 4; ++k4) {
                gi += Psm[k4][pb][pc * 4 + 0];
                gf += Psm[k4][pb][pc * 4 + 1];
                gg += Psm[k4][pb][pc * 4 + 2];
                go += Psm[k4][pb][pc * 4 + 3];
            }
            const float cprev = cst[tid];
            const float si = 1.f / (1.f + __expf(-gi));
            const float sf = 1.f / (1.f + __expf(-gf));
            const float so = 1.f / (1.f + __expf(-go));
            const float tg = 2.f / (1.f + __expf(-2.f * gg)) - 1.f;
            const float cn = sf * cprev + si * tg;
            const float th = 2.f / (1.f + __expf(-2.f * cn)) - 1.f;
            const float hn = so * th;
            cst[tid] = cn;

            // ---- publish h to ring (fragment layout), u32 pairs, agent scope ----
            const float hnb = __shfl_xor(hn, 1);
            if ((pc & 1) == 0) {
                union { _Float16 q[2]; unsigned u; } pk;
                pk.q[0] = (_Float16)hn;
                pk.q[1] = (_Float16)hnb;
                // half index = slot*32768 + (ch>>3)*512 + b*8 + (ch&7)
                const unsigned hidx = (unsigned)(t & 63) * 32768u + (unsigned)(w >> 1) * 512u
                                    + (unsigned)pb * 8u + (unsigned)((w & 1) * 4 + pc);
                __hip_atomic_store((unsigned*)(ring + hidx), pk.u,
                                   __ATOMIC_RELAXED, __HIP_MEMORY_SCOPE_AGENT);
            }
            // out store deferred to after the flag publish (off critical path)
            __builtin_amdgcn_s_waitcnt(0);
            __syncthreads();
            if (tid == 0)
                __hip_atomic_fetch_add(&done[(size_t)t * 8 + (w & 7)], 1u,
                                       __ATOMIC_RELEASE, __HIP_MEMORY_SCOPE_AGENT);
            out[(size_t)pb * (T_ * 512) + (size_t)t * 512 + gc] = hn;
        } else {
            __builtin_amdgcn_s_waitcnt(0);
            __syncthreads();
        }
    }
}

extern "C" void kernel_launch(void* const* d_in, const int* in_sizes, int n_in,
                              void* d_out, int out_size, void* d_ws, size_t ws_size,
                              hipStream_t stream) {
    const float* x   = (const float*)d_in[0];
    const float* Wih = (const float*)d_in[1];
    const float* Whh = (const float*)d_in[2];
    const float* bih = (const float*)d_in[3];
    const float* bhh = (const float*)d_in[4];
    float* out = (float*)d_out;

    char* ws = (char*)d_ws;
    unsigned*  done = (unsigned*)ws;
    _Float16*  ring = (_Float16*)(ws + OFF_RING);

    hipMemsetAsync(done, 0, T_ * 8 * sizeof(unsigned), stream);
    hipLaunchKernelGGL(lstm_persist, dim3(NWG), dim3(512), 0, stream,
                       x, Wih, Whh, bih, bhh, out, ring, done);
}